// Round 3
// baseline (380.130 us; speedup 1.0000x reference)
//
#include <hip/hip_runtime.h>
#include <math.h>

// Problem: contrastive loss over 2048 sequences.
// rep: (2048, 64, 512) f32; lens: (2048,) i32; W: (256, 512) f32; b: (256,) f32
// loss = mean_i [ lse_{k != i}(20 * z_i . z_k) - 20 * z_i . z_{partner(i)} ]
// where z = normalize(gather(rep, lens-1) @ W^T + b), partner(i) = (i + 1024) % 2048.

#define NROWS 2048
#define DDIM  512
#define PDIM  256
static constexpr float INV_T = 20.0f;   // 1 / 0.05
static constexpr float EPSN  = 1e-8f;

// ---------------------------------------------------------------------------
// Kernel 1: gather last valid token, project (x @ W^T + b), L2-normalize.
// 256 blocks x 512 threads x 8 rows. BARRIER-FREE K-loop: wave w owns output
// cols [32w, 32w+32) (lanes 0-31 -> rows 0-3, lanes 32-63 -> rows 4-7) and
// stages ITS OWN 32-col W slice into a private LDS region, so the
// ds_write -> ds_read dependency is within-wave (lgkmcnt, in-order DS pipe)
// and needs NO __syncthreads. Per-wave double-buffer (16-d half chunks) means
// the reads' lgkmcnt was drained a full compute phase earlier. Global W loads
// are register-prefetched one chunk ahead (latency hides under FMA).
// Barriers: 2 total (A-gather ready, norm cross-wave reduce). Was 33.
// Also zeroes out[0] (replaces hipMemsetAsync dispatch).
// ---------------------------------------------------------------------------
__global__ __launch_bounds__(512) void k_proj(const float* __restrict__ rep,
                                              const int*   __restrict__ lens,
                                              const float* __restrict__ W,
                                              const float* __restrict__ bias,
                                              float* __restrict__ z,
                                              float* __restrict__ out) {
  __shared__ float A[8][512];        // 16 KB gathered input rows (read-only after bar 1)
  __shared__ float Wl[2][16][257];   // 32.9 KB; wave w touches cols [32w,32w+32) only
  __shared__ float red[8][8];        // [row][wave] partial sum-of-squares

  const int t   = threadIdx.x;       // 0..511
  const int blk = blockIdx.x;        // rows blk*8 .. blk*8+7

  if (blk == 0 && t == 0) out[0] = 0.0f;   // stream-ordered before k_finish atomics

  // Gather 8 rows (1024 float4, 2 per thread, coalesced 128B/row segments).
  for (int i = 0; i < 2; ++i) {
    int e = i * 512 + t;
    int r = e >> 7;
    int q = e & 127;
    int n = blk * 8 + r;
    int idx = lens[n] - 1;
    idx = idx < 0 ? 0 : (idx > 63 ? 63 : idx);
    const float4* src = (const float4*)(rep + ((size_t)(n * 64 + idx)) * 512);
    ((float4*)&A[r][0])[q] = src[q];   // contiguous 16B/lane: linear sweep, conflict-free
  }

  const int w    = t >> 6;           // wave 0..7 -> owns cols w*32 .. w*32+31
  const int lane = t & 63;
  const int l31  = lane & 31;
  const int half = lane >> 5;        // 0: rows 0-3, 1: rows 4-7
  const int p    = w * 32 + l31;     // this lane's output column

  float acc[4];
  {
    float bv = bias[p];
    for (int r = 0; r < 4; ++r) acc[r] = bv;
  }

  // Per-wave staging map for a 16-d chunk of its 32 cols: 128 float4, 2/lane.
  // idx = i*64 + lane: c = idx>>2 (col-in-wave 0..31), dq = idx&3 (float4 in chunk).
  const int sc0 = lane >> 2,        sq0 = lane & 3;   // i = 0
  const int sc1 = 16 + (lane >> 2), sq1 = lane & 3;   // i = 1
  const float4* W4 = (const float4*)W;
  const size_t wbase0 = (size_t)(w * 32 + sc0) * 128 + sq0;   // row-major W, 128 f4/row
  const size_t wbase1 = (size_t)(w * 32 + sc1) * 128 + sq1;
  const int col0 = w * 32 + sc0, col1 = w * 32 + sc1;

  // Prologue: prefetch chunk 0.
  float4 wr0 = W4[wbase0];
  float4 wr1 = W4[wbase1];
  __syncthreads();                   // barrier 1: A fully staged

  // Write chunk 0 into buffer 0 (own region; bank = (4dq+j+c)%32 -> 2-way, free).
  Wl[0][sq0 * 4 + 0][col0] = wr0.x;
  Wl[0][sq0 * 4 + 1][col0] = wr0.y;
  Wl[0][sq0 * 4 + 2][col0] = wr0.z;
  Wl[0][sq0 * 4 + 3][col0] = wr0.w;
  Wl[0][sq1 * 4 + 0][col1] = wr1.x;
  Wl[0][sq1 * 4 + 1][col1] = wr1.y;
  Wl[0][sq1 * 4 + 2][col1] = wr1.z;
  Wl[0][sq1 * 4 + 3][col1] = wr1.w;

  for (int ci = 0; ci < 32; ++ci) {  // 32 chunks x 16 d
    const int kc = ci << 4;
    if (ci < 31) {                   // prefetch next chunk into regs
      const size_t kq = (size_t)(ci + 1) << 2;
      wr0 = W4[wbase0 + kq];
      wr1 = W4[wbase1 + kq];
    }
    const float (*Wb)[257] = Wl[ci & 1];
    for (int d4 = 0; d4 < 4; ++d4) {
      float w0 = Wb[d4 * 4 + 0][p];  // bank (d+p)%32: 32 consec p x2 broadcast -> free
      float w1 = Wb[d4 * 4 + 1][p];
      float w2 = Wb[d4 * 4 + 2][p];
      float w3 = Wb[d4 * 4 + 3][p];
      for (int r = 0; r < 4; ++r) {
        float4 av = *(const float4*)&A[half * 4 + r][kc + d4 * 4];  // wave-broadcast
        acc[r] += av.x * w0 + av.y * w1 + av.z * w2 + av.w * w3;
      }
    }
    if (ci < 31) {                   // write next chunk to other buffer (own region)
      float (*Wn)[257] = Wl[(ci + 1) & 1];
      Wn[sq0 * 4 + 0][col0] = wr0.x;
      Wn[sq0 * 4 + 1][col0] = wr0.y;
      Wn[sq0 * 4 + 2][col0] = wr0.z;
      Wn[sq0 * 4 + 3][col0] = wr0.w;
      Wn[sq1 * 4 + 0][col1] = wr1.x;
      Wn[sq1 * 4 + 1][col1] = wr1.y;
      Wn[sq1 * 4 + 2][col1] = wr1.z;
      Wn[sq1 * 4 + 3][col1] = wr1.w;
    }
  }

  // Sum of squares: per-row, 32 cols per wave-half -> shuffle, then cross-wave LDS.
  for (int r = 0; r < 4; ++r) {
    float v = acc[r] * acc[r];
    for (int off = 1; off < 32; off <<= 1) v += __shfl_xor(v, off, 64);  // within half
    if (l31 == 0) red[half * 4 + r][w] = v;
  }
  __syncthreads();                   // barrier 2: red complete
  for (int r = 0; r < 4; ++r) {
    const int g = half * 4 + r;
    float ss = red[g][0] + red[g][1] + red[g][2] + red[g][3] +
               red[g][4] + red[g][5] + red[g][6] + red[g][7];
    float nrm = sqrtf(ss);
    nrm = nrm < EPSN ? EPSN : nrm;
    z[(size_t)(blk * 8 + g) * 256 + p] = acc[r] / nrm;   // two 128B segments/wave
  }
}

// ---------------------------------------------------------------------------
// Kernel 2: SYMMETRIC 64x64 Gram tiles (upper triangle incl. diagonal, 528
// blocks). Off-diagonal tile (I<J) emits row-stats (slot (row,J)) and
// col-stats (slot (col,I)); diagonal tiles emit row-stats only (diag -inf).
// Every (row, col-block) partial slot is written exactly once.
// NOW: LDS double-buffered -> ONE barrier per chunk (8 total, was 16); global
// loads register-prefetched one chunk ahead. Stats code unchanged (verified).
// ---------------------------------------------------------------------------
__global__ __launch_bounds__(256) void k_gram(const float* __restrict__ z,
                                              float* __restrict__ mPart,
                                              float* __restrict__ sPart) {
  __shared__ float Zr[2][64][36];   // pad 36: float4-aligned, <=2-way banks (free)
  __shared__ float Zc[2][64][36];   // 36.9 KB both
  __shared__ float cred[2][4][16][4];  // [phase][wave][tx][ci]

  const int t = threadIdx.x;
  // Decode upper-triangle tile index: row I has (32 - I) tiles.
  int b = blockIdx.x;
  int I = 0;
  while (b >= 32 - I) { b -= 32 - I; ++I; }
  const int J = I + b;
  const int rb = I * 64;
  const int cb = J * 64;
  const int tx = t & 15, ty = t >> 4;
  const int wv = t >> 6;

  float acc[4][4];
  for (int i = 0; i < 4; ++i)
    for (int j = 0; j < 4; ++j) acc[i][j] = 0.0f;

  // Staging geometry: 512 float4 per buffer per chunk, 256 threads -> 2 each.
  const float4* z4 = (const float4*)z;
  const int srow0 = t >> 3,        sdq0 = t & 7;        // idx = t
  const int srow1 = 32 + (t >> 3), sdq1 = t & 7;        // idx = 256 + t

  float4 rr0, rr1, cr0, cr1;
  // Prologue: prefetch + write chunk 0 into buffer 0.
  rr0 = z4[(size_t)(rb + srow0) * 64 + sdq0];
  rr1 = z4[(size_t)(rb + srow1) * 64 + sdq1];
  cr0 = z4[(size_t)(cb + srow0) * 64 + sdq0];
  cr1 = z4[(size_t)(cb + srow1) * 64 + sdq1];
  *(float4*)&Zr[0][srow0][sdq0 * 4] = rr0;
  *(float4*)&Zr[0][srow1][sdq1 * 4] = rr1;
  *(float4*)&Zc[0][srow0][sdq0 * 4] = cr0;
  *(float4*)&Zc[0][srow1][sdq1 * 4] = cr1;
  __syncthreads();

  for (int c = 0; c < 8; ++c) {      // 8 chunks x 32 d
    if (c < 7) {                     // prefetch next chunk into regs
      const size_t kq = (size_t)(c + 1) * 8;
      rr0 = z4[(size_t)(rb + srow0) * 64 + kq + sdq0];
      rr1 = z4[(size_t)(rb + srow1) * 64 + kq + sdq1];
      cr0 = z4[(size_t)(cb + srow0) * 64 + kq + sdq0];
      cr1 = z4[(size_t)(cb + srow1) * 64 + kq + sdq1];
    }
    const float (*ZrC)[36] = Zr[c & 1];
    const float (*ZcC)[36] = Zc[c & 1];
    for (int d4 = 0; d4 < 32; d4 += 4) {
      float4 a0 = *(const float4*)&ZrC[ty +  0][d4];
      float4 a1 = *(const float4*)&ZrC[ty + 16][d4];
      float4 a2 = *(const float4*)&ZrC[ty + 32][d4];
      float4 a3 = *(const float4*)&ZrC[ty + 48][d4];
      float4 b0 = *(const float4*)&ZcC[tx +  0][d4];
      float4 b1 = *(const float4*)&ZcC[tx + 16][d4];
      float4 b2 = *(const float4*)&ZcC[tx + 32][d4];
      float4 b3 = *(const float4*)&ZcC[tx + 48][d4];
#define DOT4(u, v) (u.x * v.x + u.y * v.y + u.z * v.z + u.w * v.w)
      acc[0][0] += DOT4(a0, b0); acc[0][1] += DOT4(a0, b1);
      acc[0][2] += DOT4(a0, b2); acc[0][3] += DOT4(a0, b3);
      acc[1][0] += DOT4(a1, b0); acc[1][1] += DOT4(a1, b1);
      acc[1][2] += DOT4(a1, b2); acc[1][3] += DOT4(a1, b3);
      acc[2][0] += DOT4(a2, b0); acc[2][1] += DOT4(a2, b1);
      acc[2][2] += DOT4(a2, b2); acc[2][3] += DOT4(a2, b3);
      acc[3][0] += DOT4(a3, b0); acc[3][1] += DOT4(a3, b1);
      acc[3][2] += DOT4(a3, b2); acc[3][3] += DOT4(a3, b3);
#undef DOT4
    }
    if (c < 7) {                     // write next chunk to other buffer
      float (*ZrN)[36] = Zr[(c + 1) & 1];
      float (*ZcN)[36] = Zc[(c + 1) & 1];
      *(float4*)&ZrN[srow0][sdq0 * 4] = rr0;
      *(float4*)&ZrN[srow1][sdq1 * 4] = rr1;
      *(float4*)&ZcN[srow0][sdq0 * 4] = cr0;
      *(float4*)&ZcN[srow1][sdq1 * 4] = cr1;
      __syncthreads();               // RAW for c+1; WAR safe (prev reads pre-barrier)
    }
  }

  // Masked, temperature-scaled logit values (diag only possible when I==J).
  float v[4][4];
  for (int ri = 0; ri < 4; ++ri) {
    const int grow = rb + ty + 16 * ri;
    for (int ci = 0; ci < 4; ++ci) {
      const int gcol = cb + tx + 16 * ci;
      v[ri][ci] = (grow == gcol) ? -INFINITY : acc[ri][ci] * INV_T;
    }
  }

  // ---- Row stats (rows of block I over this tile's 64 cols) -> slot (row, J)
  for (int ri = 0; ri < 4; ++ri) {
    const int grow = rb + ty + 16 * ri;
    float m = -INFINITY;
    for (int ci = 0; ci < 4; ++ci) m = fmaxf(m, v[ri][ci]);
    for (int off = 1; off < 16; off <<= 1) m = fmaxf(m, __shfl_xor(m, off, 64));
    float s = 0.0f;
    for (int ci = 0; ci < 4; ++ci)
      s += (v[ri][ci] == -INFINITY) ? 0.0f : __expf(v[ri][ci] - m);
    for (int off = 1; off < 16; off <<= 1) s += __shfl_xor(s, off, 64);
    if (tx == 0) {
      mPart[(size_t)grow * 32 + J] = m;
      sPart[(size_t)grow * 32 + J] = s;
    }
  }

  // ---- Col stats (rows of block J over cols of block I) -> slot (col, I)
  if (I != J) {
    // Phase 1: column max over the 64 rows.
    float cm[4];
    for (int ci = 0; ci < 4; ++ci) {
      float m = v[0][ci];
      for (int ri = 1; ri < 4; ++ri) m = fmaxf(m, v[ri][ci]);
      m = fmaxf(m, __shfl_xor(m, 16, 64));   // reduce over ty within wave
      m = fmaxf(m, __shfl_xor(m, 32, 64));
      cm[ci] = m;
    }
    if ((t & 48) == 0)                        // one ty-representative per wave
      for (int ci = 0; ci < 4; ++ci) cred[0][wv][tx][ci] = cm[ci];
    __syncthreads();
    float M[4];
    for (int ci = 0; ci < 4; ++ci) {
      float m = cred[0][0][tx][ci];
      for (int w = 1; w < 4; ++w) m = fmaxf(m, cred[0][w][tx][ci]);
      M[ci] = m;
    }
    // Phase 2: column sum of exp.
    float cs[4];
    for (int ci = 0; ci < 4; ++ci) {
      float s = 0.0f;
      for (int ri = 0; ri < 4; ++ri) s += __expf(v[ri][ci] - M[ci]);
      s += __shfl_xor(s, 16, 64);
      s += __shfl_xor(s, 32, 64);
      cs[ci] = s;
    }
    if ((t & 48) == 0)
      for (int ci = 0; ci < 4; ++ci) cred[1][wv][tx][ci] = cs[ci];
    __syncthreads();
    if (t < 16) {                             // ty == 0 threads write 64 cols
      for (int ci = 0; ci < 4; ++ci) {
        float s = cred[1][0][tx][ci] + cred[1][1][tx][ci] +
                  cred[1][2][tx][ci] + cred[1][3][tx][ci];
        const int gcol = cb + tx + 16 * ci;
        mPart[(size_t)gcol * 32 + I] = M[ci];
        sPart[(size_t)gcol * 32 + I] = s;
      }
    }
  }
}

// ---------------------------------------------------------------------------
// Kernel 3: combine 32 partials per row -> lse; positive dot; mean via atomic.
// One wave per row (4 rows / block); block-level LDS reduce -> 1 atomic/block.
// ---------------------------------------------------------------------------
__global__ __launch_bounds__(256) void k_finish(const float* __restrict__ z,
                                                const float* __restrict__ mPart,
                                                const float* __restrict__ sPart,
                                                float* __restrict__ out) {
  __shared__ float red[4];
  const int t = threadIdx.x;
  const int wid = t >> 6, lane = t & 63;
  const int row = blockIdx.x * 4 + wid;

  float m = (lane < 32) ? mPart[(size_t)row * 32 + lane] : -INFINITY;
  float s = (lane < 32) ? sPart[(size_t)row * 32 + lane] : 0.0f;
  float M = m;
  for (int off = 1; off < 64; off <<= 1) M = fmaxf(M, __shfl_xor(M, off, 64));
  float se = (lane < 32) ? s * __expf(m - M) : 0.0f;
  for (int off = 1; off < 64; off <<= 1) se += __shfl_xor(se, off, 64);
  float lse = M + logf(se);

  const int partner = row < 1024 ? row + 1024 : row - 1024;
  float4 a = ((const float4*)(z + (size_t)row * 256))[lane];
  float4 b = ((const float4*)(z + (size_t)partner * 256))[lane];
  float d = a.x * b.x + a.y * b.y + a.z * b.z + a.w * b.w;
  for (int off = 1; off < 64; off <<= 1) d += __shfl_xor(d, off, 64);

  if (lane == 0) red[wid] = lse - d * INV_T;
  __syncthreads();
  if (t == 0)
    atomicAdd(out, (red[0] + red[1] + red[2] + red[3]) * (1.0f / 2048.0f));
}

// ---------------------------------------------------------------------------
extern "C" void kernel_launch(void* const* d_in, const int* in_sizes, int n_in,
                              void* d_out, int out_size, void* d_ws, size_t ws_size,
                              hipStream_t stream) {
  const float* rep  = (const float*)d_in[0];
  const int*   lens = (const int*)  d_in[1];
  const float* W    = (const float*)d_in[2];
  const float* bias = (const float*)d_in[3];
  float* out = (float*)d_out;

  float* z     = (float*)d_ws;            // 2048*256 f32 = 2 MB
  float* mPart = z + NROWS * PDIM;        // 2048*32 f32
  float* sPart = mPart + NROWS * 32;      // 2048*32 f32

  k_proj  <<<256, 512, 0, stream>>>(rep, lens, W, bias, z, out);
  k_gram  <<<528, 256, 0, stream>>>(z, mPart, sPart);
  k_finish<<<512, 256, 0, stream>>>(z, mPart, sPart, out);
}